// Round 3
// baseline (606.339 us; speedup 1.0000x reference)
//
#include <hip/hip_runtime.h>
#include <hip/hip_bf16.h>
#include <math.h>

#define NB 16
#define NN 24
#define NA (NB*NN)   /* 384 atoms total */
#define FF 128
#define CC 27
#define MAXNBR 32    /* provably <= 23 neighbors possible (image spacing L > 2r) */

// ---- static device scratch (d_ws unused; everything read is rewritten each call) ----
__device__ int    g_isf32;
__device__ int    g_cnt[NA];
__device__ float  g_radius[NB];
__device__ float  g_sigma[4];
__device__ int    g_nj[NA*MAXNBR];
__device__ float  g_nd[NA*MAXNBR];
__device__ float  g_nw[NA*MAXNBR];
__device__ float  g_featA[NA*FF];
__device__ float  g_featB[NA*FF];
__device__ float  g_proj[NA*4*FF];
__device__ float  g_h[NB*FF];

__device__ __forceinline__ float ld(const void* p, int idx, int f32) {
  return f32 ? ((const float*)p)[idx]
             : __bfloat162float(((const __hip_bfloat16*)p)[idx]);
}
__device__ __forceinline__ float softplusf(float x){ return fmaxf(x,0.f) + log1pf(expf(-fabsf(x))); }
__device__ __forceinline__ float sigmoidf(float x){ return 1.f/(1.f+expf(-x)); }

// ---------------- dtype detect: cell[0][0][0] = L in [8,10] iff buffer is fp32 ----------
__global__ void k_detect(const void* cell) {
  float v = ((const float*)cell)[0];
  g_isf32 = (v > 1.0f && v < 100.0f) ? 1 : 0;
}

// ---------------- init: zero nbr counters, radius per batch, feat0 = tanh(emb[z-1]) ------
__global__ void k_init(const void* __restrict__ cell,
                       const void* __restrict__ emb,
                       const int* __restrict__ z) {
  int f32 = g_isf32;
  int t = blockIdx.x*blockDim.x + threadIdx.x;
  if (t < NA) g_cnt[t] = 0;
  if (t < NB) {
    float c[9];
    #pragma unroll
    for (int k=0;k<9;k++) c[k] = ld(cell, t*9+k, f32);
    float cx = c[4]*c[8] - c[5]*c[7];
    float cy = c[5]*c[6] - c[3]*c[8];
    float cz = c[3]*c[7] - c[4]*c[6];
    float vol = c[0]*cx + c[1]*cy + c[2]*cz;
    g_radius[t] = cbrtf(fabsf(vol)/(float)NN);   // RADIUS_RATE = 1
  }
  if (t < NA*FF) {
    int a = t/FF, fc = t-a*FF;
    int zi = z[a]; if (zi < 1) zi = 1; if (zi > 100) zi = 100;
    g_featA[t] = tanhf(ld(emb, (zi-1)*FF+fc, f32));
  }
}

// ---------------- neighbor list: block per target atom i ----------------
__global__ void k_nbr(const void* __restrict__ pos,
                      const void* __restrict__ cell) {
  int f32 = g_isf32;
  int i = blockIdx.x;
  int b = i / NN;
  float pix = ld(pos, i*3+0, f32);
  float piy = ld(pos, i*3+1, f32);
  float piz = ld(pos, i*3+2, f32);
  float rb  = g_radius[b];
  float rb2 = rb*rb;
  float cl[9];
  #pragma unroll
  for (int k=0;k<9;k++) cl[k] = ld(cell, b*9+k, f32);
  const float PI = 3.14159265358979323846f;
  for (int cand = threadIdx.x; cand < NN*CC; cand += blockDim.x) {
    int j = cand / CC, c = cand - j*CC;
    float gx = (float)(c/9) - 1.0f;
    float gy = (float)((c/3)%3) - 1.0f;
    float gz = (float)(c%3) - 1.0f;
    float ox = gx*cl[0] + gy*cl[3] + gz*cl[6];
    float oy = gx*cl[1] + gy*cl[4] + gz*cl[7];
    float oz = gx*cl[2] + gy*cl[5] + gz*cl[8];
    int jg = b*NN + j;
    float dx = pix - (ld(pos, jg*3+0, f32) + ox);
    float dy = piy - (ld(pos, jg*3+1, f32) + oy);
    float dz = piz - (ld(pos, jg*3+2, f32) + oz);
    float d2 = dx*dx + dy*dy + dz*dz;
    if (d2 <= rb2 && d2 > 1e-4f) {
      float dist = sqrtf(fmaxf(d2, 1e-12f));
      float w = cosf(dist*PI/rb) + 1.0f;
      int slot = atomicAdd(&g_cnt[i], 1);
      if (slot < MAXNBR) {
        g_nj[i*MAXNBR+slot] = jg;
        g_nd[i*MAXNBR+slot] = dist;
        g_nw[i*MAXNBR+slot] = w;
      }
    }
  }
}

// ------- projections: gi,gj,si,sj = feat @ {Wf[:F],Wf[F:2F],Ws[:F],Ws[F:2F]} -------
__global__ void k_proj(int layer,
                       const void* __restrict__ convWf,  // (3, 3F, F)
                       const void* __restrict__ convWs) {
  int f32 = g_isf32;
  int base = layer*3*FF*FF;
  const float* feat = (layer & 1) ? g_featB : g_featA;
  int i = blockIdx.x; int f = threadIdx.x;
  __shared__ float ft[FF];
  ft[f] = feat[i*FF+f];
  __syncthreads();
  float gi=0.f, gj=0.f, si=0.f, sj=0.f;
  #pragma unroll 4
  for (int k=0;k<FF;k++) {
    float a = ft[k];
    gi += a * ld(convWf, base + k*FF+f, f32);
    gj += a * ld(convWf, base + (FF+k)*FF+f, f32);
    si += a * ld(convWs, base + k*FF+f, f32);
    sj += a * ld(convWs, base + (FF+k)*FF+f, f32);
  }
  g_proj[(i*4+0)*FF+f] = gi;
  g_proj[(i*4+1)*FF+f] = gj;
  g_proj[(i*4+2)*FF+f] = si;
  g_proj[(i*4+3)*FF+f] = sj;
}

// ---------------- conv: accumulate messages over neighbor list ----------------
__global__ void k_conv(int layer,
                       const void* __restrict__ convWf,
                       const void* __restrict__ convWs,
                       const void* __restrict__ convbf,
                       const void* __restrict__ convbs) {
  int f32 = g_isf32;
  int wbase = layer*3*FF*FF + 2*FF*FF;   // W[2F:] slice
  const float* feat    = (layer & 1) ? g_featB : g_featA;
  float*       featOut = (layer & 1) ? g_featA : g_featB;
  int i = blockIdx.x; int f = threadIdx.x;
  __shared__ float ea[FF];
  const float step = 6.0f/127.0f;
  const float coeff = -0.5f/(step*step);
  float gif = g_proj[(i*4+0)*FF+f];
  float sif = g_proj[(i*4+2)*FF+f];
  float bff = ld(convbf, layer*FF+f, f32);
  float bsf = ld(convbs, layer*FF+f, f32);
  float myg = step*(float)f;
  float acc = 0.f;
  int n = g_cnt[i]; if (n > MAXNBR) n = MAXNBR; if (n < 0) n = 0;
  for (int e=0;e<n;e++) {
    int   jg  = g_nj[i*MAXNBR+e];
    float dist= g_nd[i*MAXNBR+e];
    float w   = g_nw[i*MAXNBR+e];
    __syncthreads();
    float dd = dist - myg;
    ea[f] = expf(coeff*dd*dd);
    __syncthreads();
    float ge=0.f, se=0.f;
    #pragma unroll 4
    for (int k=0;k<FF;k++) {
      float a = ea[k];
      ge += a * ld(convWf, wbase + k*FF+f, f32);
      se += a * ld(convWs, wbase + k*FF+f, f32);
    }
    float g = sigmoidf(gif + g_proj[(jg*4+1)*FF+f] + ge + bff);
    float s = softplusf(sif + g_proj[(jg*4+3)*FF+f] + se + bsf);
    acc += g*s*w;
  }
  featOut[i*FF+f] = softplusf(feat[i*FF+f] + acc);
}

// ---------------- per-batch mean over atoms (featB holds layer-3 output) ----------------
__global__ void k_mean() {
  int b = blockIdx.x, f = threadIdx.x;
  float s = 0.f;
  for (int n=0;n<NN;n++) s += g_featB[(b*NN+n)*FF+f];
  g_h[b*FF+f] = s/(float)NN;
}

// ------- spectral-norm sigma per FC layer (power iteration, 5 iters, eps=1e-12) -------
__global__ void k_sigma(const void* __restrict__ fcW) {
  int f32 = g_isf32;
  int l = blockIdx.x, t = threadIdx.x;
  const int Wb = l*FF*FF;
  __shared__ float u[FF], v[FF], red[FF];
  u[t] = 1.0f/sqrtf((float)FF);
  __syncthreads();
  for (int it=0; it<5; it++) {
    float s = 0.f;
    for (int c=0;c<FF;c++) s += ld(fcW, Wb + t*FF+c, f32) * u[c];
    v[t] = s; red[t] = s*s;
    __syncthreads();
    for (int st=64; st>0; st>>=1) { if (t<st) red[t]+=red[t+st]; __syncthreads(); }
    float nv = sqrtf(red[0]) + 1e-12f;
    __syncthreads();
    v[t] = v[t]/nv;
    __syncthreads();
    float s2 = 0.f;
    for (int r=0;r<FF;r++) s2 += ld(fcW, Wb + r*FF+t, f32) * v[r];
    u[t] = s2; red[t] = s2*s2;
    __syncthreads();
    for (int st=64; st>0; st>>=1) { if (t<st) red[t]+=red[t+st]; __syncthreads(); }
    float nu = sqrtf(red[0]) + 1e-12f;
    __syncthreads();
    u[t] = u[t]/nu;
    __syncthreads();
  }
  float s = 0.f;
  for (int c=0;c<FF;c++) s += ld(fcW, Wb + t*FF+c, f32) * u[c];
  red[t] = v[t]*s;
  __syncthreads();
  for (int st=64; st>0; st>>=1) { if (t<st) red[t]+=red[t+st]; __syncthreads(); }
  if (t==0) g_sigma[l] = red[0];
}

// ---------------- FC chain + linear head, one block per batch ----------------
__global__ void k_fc(const void* __restrict__ fcW,
                     const void* __restrict__ fcb,
                     const void* __restrict__ Wout,
                     const void* __restrict__ bout,
                     void* __restrict__ out) {
  int f32 = g_isf32;
  int b = blockIdx.x, f = threadIdx.x;
  __shared__ float hh[FF], tmp[FF], red[FF];
  hh[f] = g_h[b*FF+f];
  __syncthreads();
  for (int l=0;l<3;l++) {
    float inv_s = 1.0f/g_sigma[l];
    float s = 0.f;
    #pragma unroll 4
    for (int k=0;k<FF;k++) s += hh[k]*ld(fcW, l*FF*FF + k*FF+f, f32);
    float x = s*inv_s + ld(fcb, l*FF+f, f32);
    tmp[f] = softplusf(x);
    __syncthreads();
    hh[f] = tmp[f];
    __syncthreads();
  }
  red[f] = hh[f]*ld(Wout, f, f32);
  __syncthreads();
  for (int st=64; st>0; st>>=1) { if (f<st) red[f]+=red[f+st]; __syncthreads(); }
  if (f==0) {
    float val = red[0] + ld(bout, 0, f32);
    if (f32) ((float*)out)[b] = val;
    else     ((__hip_bfloat16*)out)[b] = __float2bfloat16(val);
  }
}

extern "C" void kernel_launch(void* const* d_in, const int* in_sizes, int n_in,
                              void* d_out, int out_size, void* d_ws, size_t ws_size,
                              hipStream_t stream) {
  const void* pos     = d_in[0];
  const void* cell    = d_in[1];
  const void* emb     = d_in[2];
  const void* conv_Wf = d_in[3];
  const void* conv_bf = d_in[4];
  const void* conv_Ws = d_in[5];
  const void* conv_bs = d_in[6];
  const void* fc_W    = d_in[7];
  const void* fc_b    = d_in[8];
  const void* W_out   = d_in[9];
  const void* b_out   = d_in[10];
  const int*  z       = (const int*)d_in[11];
  // d_in[12] = batch (unused); d_ws unused (static device scratch)

  k_detect<<<1, 1, 0, stream>>>(cell);
  k_init<<<192, 256, 0, stream>>>(cell, emb, z);
  k_nbr<<<NA, 256, 0, stream>>>(pos, cell);

  for (int l=0; l<3; l++) {
    k_proj<<<NA, FF, 0, stream>>>(l, conv_Wf, conv_Ws);
    k_conv<<<NA, FF, 0, stream>>>(l, conv_Wf, conv_Ws, conv_bf, conv_bs);
  }

  k_mean<<<NB, FF, 0, stream>>>();
  k_sigma<<<3, FF, 0, stream>>>(fc_W);
  k_fc<<<NB, FF, 0, stream>>>(fc_W, fc_b, W_out, b_out, d_out);
}

// Round 4
// 222.770 us; speedup vs baseline: 2.7218x; 2.7218x over previous
//
#include <hip/hip_runtime.h>
#include <hip/hip_bf16.h>
#include <math.h>

#define NB 16
#define NN 24
#define NA (NB*NN)   /* 384 atoms */
#define FF 128
#define CC 27
#define MAXNBR 32    /* physically <= 23 possible (image spacing L > 2r) */

// ---- static device scratch (d_ws unused; everything read is rewritten every call) ----
__device__ int   g_cnt[NA];
__device__ float g_radius[NB];
__device__ float g_sigma[4];
__device__ int   g_nj[NA*MAXNBR];
__device__ float g_nd[NA*MAXNBR];
__device__ float g_nw[NA*MAXNBR];
__device__ float g_featA[NA*FF];
__device__ float g_featB[NA*FF];
__device__ float g_proj[NA*4*FF];   // per atom: gi, gj, si, sj
__device__ float g_acc[NA*FF];      // message accumulator

__device__ __forceinline__ float softplusf(float x){ return fmaxf(x,0.f) + log1pf(expf(-fabsf(x))); }
__device__ __forceinline__ float sigmoidf(float x){ return 1.f/(1.f+expf(-x)); }

// -------- init: nbr counters, radius per batch, feat0 = tanh(emb[z-1]) --------
__global__ void k_init(const float* __restrict__ cell,
                       const float* __restrict__ emb,
                       const int* __restrict__ z) {
  int t = blockIdx.x*blockDim.x + threadIdx.x;   // 192*256 = NA*FF
  if (t < NA) g_cnt[t] = 0;
  if (t < NB) {
    float c[9];
    #pragma unroll
    for (int k=0;k<9;k++) c[k] = cell[t*9+k];
    float cx = c[4]*c[8] - c[5]*c[7];
    float cy = c[5]*c[6] - c[3]*c[8];
    float cz = c[3]*c[7] - c[4]*c[6];
    float vol = c[0]*cx + c[1]*cy + c[2]*cz;
    g_radius[t] = cbrtf(fabsf(vol)/(float)NN);   // RADIUS_RATE = 1
  }
  int a = t/FF, fc = t-a*FF;
  int zi = z[a]; if (zi < 1) zi = 1; if (zi > 100) zi = 100;
  g_featA[t] = tanhf(emb[(zi-1)*FF+fc]);
}

// -------- neighbor list: block per target atom i --------
__global__ void k_nbr(const float* __restrict__ pos,
                      const float* __restrict__ cell) {
  int i = blockIdx.x;
  int b = i / NN;
  float pix = pos[i*3+0], piy = pos[i*3+1], piz = pos[i*3+2];
  float rb  = g_radius[b];
  float rb2 = rb*rb;
  float cl[9];
  #pragma unroll
  for (int k=0;k<9;k++) cl[k] = cell[b*9+k];
  const float PI = 3.14159265358979323846f;
  for (int cand = threadIdx.x; cand < NN*CC; cand += blockDim.x) {
    int j = cand / CC, c = cand - j*CC;
    float gx = (float)(c/9) - 1.0f;
    float gy = (float)((c/3)%3) - 1.0f;
    float gz = (float)(c%3) - 1.0f;
    float ox = gx*cl[0] + gy*cl[3] + gz*cl[6];
    float oy = gx*cl[1] + gy*cl[4] + gz*cl[7];
    float oz = gx*cl[2] + gy*cl[5] + gz*cl[8];
    int jg = b*NN + j;
    float dx = pix - (pos[jg*3+0] + ox);
    float dy = piy - (pos[jg*3+1] + oy);
    float dz = piz - (pos[jg*3+2] + oz);
    float d2 = dx*dx + dy*dy + dz*dz;
    if (d2 <= rb2 && d2 > 1e-4f) {
      float dist = sqrtf(fmaxf(d2, 1e-12f));
      float w = cosf(dist*PI/rb) + 1.0f;
      int slot = atomicAdd(&g_cnt[i], 1);
      if (slot < MAXNBR) {
        g_nj[i*MAXNBR+slot] = jg;
        g_nd[i*MAXNBR+slot] = dist;
        g_nw[i*MAXNBR+slot] = w;
      }
    }
  }
}

// -------- projections: block per (atom, which∈{gi,gj,si,sj}); also zeroes g_acc --------
__global__ void k_proj(int layer,
                       const float* __restrict__ convWf,
                       const float* __restrict__ convWs) {
  int bid = blockIdx.x;            // 0..4*NA-1
  int i = bid >> 2, which = bid & 3;
  int f = threadIdx.x;
  const float* feat = (layer & 1) ? g_featB : g_featA;
  int base = layer*3*FF*FF;
  const float* W;
  if      (which == 0) W = convWf + base;           // gi: Wf[:F]
  else if (which == 1) W = convWf + base + FF*FF;   // gj: Wf[F:2F]
  else if (which == 2) W = convWs + base;           // si: Ws[:F]
  else                 W = convWs + base + FF*FF;   // sj: Ws[F:2F]
  __shared__ float ft[FF];
  ft[f] = feat[i*FF+f];
  if (which == 0) g_acc[i*FF+f] = 0.f;
  __syncthreads();
  float s = 0.f;
  #pragma unroll 16
  for (int k=0;k<FF;k++) s += ft[k] * W[k*FF+f];
  g_proj[(i*4+which)*FF+f] = s;
}

// -------- one block per (atom, edge slot): banded Gaussian + gate/filter + atomic acc ----
__global__ void k_edge(int layer,
                       const float* __restrict__ convWf,
                       const float* __restrict__ convWs,
                       const float* __restrict__ convbf,
                       const float* __restrict__ convbs) {
  int bid = blockIdx.x;            // NA*MAXNBR
  int i = bid >> 5, e = bid & (MAXNBR-1);
  int n = g_cnt[i]; if (n > MAXNBR) n = MAXNBR;
  if (e >= n) return;
  int f = threadIdx.x;
  int   jg   = g_nj[i*MAXNBR+e];
  float dist = g_nd[i*MAXNBR+e];
  float w    = g_nw[i*MAXNBR+e];
  const float step  = 6.0f/127.0f;
  const float coeff = -0.5f/(step*step);
  int wb = layer*3*FF*FF + 2*FF*FF;          // W[2F:] slice
  const float* Wf2 = convWf + wb;
  const float* Ws2 = convWs + wb;
  // Gaussian band: |dist - k*step| > 9*step contributes < 2e-18 -> exact in fp32
  float center = dist / step;
  int kmin = (int)ceilf(center - 9.0f);  if (kmin < 0)   kmin = 0;
  int kmax = (int)floorf(center + 9.0f); if (kmax > 127) kmax = 127;
  float ge = 0.f, se = 0.f;
  for (int k = kmin; k <= kmax; k++) {
    float dd = dist - step*(float)k;
    float a  = expf(coeff*dd*dd);
    ge += a * Wf2[k*FF+f];
    se += a * Ws2[k*FF+f];
  }
  float g = sigmoidf(g_proj[(i*4+0)*FF+f] + g_proj[(jg*4+1)*FF+f] + ge + convbf[layer*FF+f]);
  float s = softplusf(g_proj[(i*4+2)*FF+f] + g_proj[(jg*4+3)*FF+f] + se + convbs[layer*FF+f]);
  atomicAdd(&g_acc[i*FF+f], g*s*w);
}

// -------- feat update: softplus(feat + acc) --------
__global__ void k_post(int layer) {
  int t = blockIdx.x*blockDim.x + threadIdx.x;   // NA*FF
  const float* feat = (layer & 1) ? g_featB : g_featA;
  float*       out  = (layer & 1) ? g_featA : g_featB;
  out[t] = softplusf(feat[t] + g_acc[t]);
}

// -------- spectral-norm sigma: W cached in LDS (stride 129 -> conflict-free) --------
__global__ void k_sigma(const float* __restrict__ fcW) {
  int l = blockIdx.x, t = threadIdx.x;           // block 128
  const float* W = fcW + l*FF*FF;
  __shared__ float w[FF*129];
  __shared__ float u[FF], v[FF], red[FF];
  for (int r=0;r<FF;r++) w[r*129+t] = W[r*FF+t]; // coalesced fill
  u[t] = 1.0f/sqrtf((float)FF);                  // ones / ||ones||
  __syncthreads();
  for (int it=0; it<5; it++) {
    float s = 0.f;
    #pragma unroll 8
    for (int c=0;c<FF;c++) s += w[t*129+c] * u[c];      // v = W u
    v[t] = s; red[t] = s*s;
    __syncthreads();
    for (int st=64; st>0; st>>=1) { if (t<st) red[t]+=red[t+st]; __syncthreads(); }
    float nv = sqrtf(red[0]) + 1e-12f;
    __syncthreads();
    v[t] = v[t]/nv;
    __syncthreads();
    float s2 = 0.f;
    #pragma unroll 8
    for (int r=0;r<FF;r++) s2 += w[r*129+t] * v[r];     // u = W^T v
    u[t] = s2; red[t] = s2*s2;
    __syncthreads();
    for (int st=64; st>0; st>>=1) { if (t<st) red[t]+=red[t+st]; __syncthreads(); }
    float nu = sqrtf(red[0]) + 1e-12f;
    __syncthreads();
    u[t] = u[t]/nu;
    __syncthreads();
  }
  float s = 0.f;
  #pragma unroll 8
  for (int c=0;c<FF;c++) s += w[t*129+c] * u[c];
  red[t] = v[t]*s;
  __syncthreads();
  for (int st=64; st>0; st>>=1) { if (t<st) red[t]+=red[t+st]; __syncthreads(); }
  if (t==0) g_sigma[l] = red[0];
}

// -------- mean over atoms + FC chain + head, one block per batch --------
__global__ void k_meanfc(const float* __restrict__ fcW,
                         const float* __restrict__ fcb,
                         const float* __restrict__ Wout,
                         const float* __restrict__ bout,
                         float* __restrict__ out) {
  int b = blockIdx.x, f = threadIdx.x;
  __shared__ float hh[FF], tmp[FF], red[FF];
  float s0 = 0.f;
  for (int n=0;n<NN;n++) s0 += g_featB[(b*NN+n)*FF+f];  // featB = layer-3 output
  hh[f] = s0/(float)NN;
  __syncthreads();
  for (int l=0;l<3;l++) {
    float inv_s = 1.0f/g_sigma[l];
    float s = 0.f;
    #pragma unroll 8
    for (int k=0;k<FF;k++) s += hh[k]*fcW[l*FF*FF + k*FF+f];
    float x = s*inv_s + fcb[l*FF+f];
    tmp[f] = softplusf(x);
    __syncthreads();
    hh[f] = tmp[f];
    __syncthreads();
  }
  red[f] = hh[f]*Wout[f];
  __syncthreads();
  for (int st=64; st>0; st>>=1) { if (f<st) red[f]+=red[f+st]; __syncthreads(); }
  if (f==0) out[b] = red[0] + bout[0];
}

extern "C" void kernel_launch(void* const* d_in, const int* in_sizes, int n_in,
                              void* d_out, int out_size, void* d_ws, size_t ws_size,
                              hipStream_t stream) {
  const float* pos     = (const float*)d_in[0];
  const float* cell    = (const float*)d_in[1];
  const float* emb     = (const float*)d_in[2];
  const float* conv_Wf = (const float*)d_in[3];
  const float* conv_bf = (const float*)d_in[4];
  const float* conv_Ws = (const float*)d_in[5];
  const float* conv_bs = (const float*)d_in[6];
  const float* fc_W    = (const float*)d_in[7];
  const float* fc_b    = (const float*)d_in[8];
  const float* W_out   = (const float*)d_in[9];
  const float* b_out   = (const float*)d_in[10];
  const int*   z       = (const int*)d_in[11];
  // d_in[12] = batch (unused); d_ws unused (static device scratch)
  // All tensors fp32 (validated R3: absmax == 0.0 vs np reference with fp32 reads)

  k_init<<<192, 256, 0, stream>>>(cell, emb, z);
  k_nbr<<<NA, 256, 0, stream>>>(pos, cell);

  for (int l=0; l<3; l++) {
    k_proj<<<NA*4,      FF,  0, stream>>>(l, conv_Wf, conv_Ws);
    k_edge<<<NA*MAXNBR, FF,  0, stream>>>(l, conv_Wf, conv_Ws, conv_bf, conv_bs);
    k_post<<<192,       256, 0, stream>>>(l);
  }

  k_sigma<<<3, FF, 0, stream>>>(fc_W);
  k_meanfc<<<NB, FF, 0, stream>>>(fc_W, fc_b, W_out, b_out, (float*)d_out);
}